// Round 6
// baseline (15.049 us; speedup 1.0000x reference)
//
#include <hip/hip_runtime.h>

#if __has_builtin(__builtin_amdgcn_exp2f)
#define EXP2F(x) __builtin_amdgcn_exp2f(x)
#else
#define EXP2F(x) exp2f(x)
#endif

typedef float v2f __attribute__((ext_vector_type(2)));

constexpr float L2E = 1.4426950408889634f;
constexpr float CD  = -500.0f * L2E;   // -0.5/0.001 * log2(e)
#define MAXP 256                       // max Gaussian pairs (M <= 512)

static __device__ __forceinline__ v2f mk2(float x, float y) {
    v2f r; r.x = x; r.y = y; return r;
}

// Single fused kernel. Block = 512 threads = 8 waves, covers 256 points
// (4 points per thread -> each broadcast ds_read_b128 feeds 8 point-gauss
// evals, 2-wide packed). Grid = N/256 = 256 blocks = 1 block/CU.
// Phase 1: threads 0..P-1 expand one Gaussian PAIR each into LDS
//          (pair-transposed coefficients, 4 x float4 per pair).
// Phase 2: wave w sums pair-chunk w (P/8 pairs) for its 4x64 points.
// exponent(log2) = c0*px^2 + c1*py^2 + c2*px + c3*py + c4*dx + c5*dy + c6 + K
__global__ __launch_bounds__(512, 4)
void decoder_fused(const float* __restrict__ origins,
                   const float* __restrict__ directions,
                   const float* __restrict__ latents,
                   float* __restrict__ out, int N, int M, int P)
{
    __shared__ float4 lcf[MAXP * 4];
    __shared__ float  psum[8 * 256];   // [wave][pt*64 + lane]

    const int tid = threadIdx.x;

    // ---- Phase 1: expand coefficients into LDS (once per block) ----
    if (tid < P) {
        float c[2][7];
        #pragma unroll
        for (int h = 0; h < 2; ++h) {
            int j = 2 * tid + h;
            if (j < M) {
                const float* L = latents + j * 6;
                float mx = L[0], my = L[1], mdx = L[2], mdy = L[3];
                float A = (-0.5f * L2E) / (fmaxf(L[4], 0.0f) + 0.01f);
                float B = (-0.5f * L2E) / (fmaxf(L[5], 0.0f) + 0.01f);
                c[h][0] = A;
                c[h][1] = B;
                c[h][2] = -2.0f * A * mx;
                c[h][3] = -2.0f * B * my;
                c[h][4] = -2.0f * CD * mdx;
                c[h][5] = -2.0f * CD * mdy;
                c[h][6] = A*mx*mx + B*my*my + CD*(mdx*mdx + mdy*mdy);
            } else {
                c[h][0] = c[h][1] = c[h][2] = c[h][3] = c[h][4] = c[h][5] = 0.0f;
                c[h][6] = -3.0e38f;   // exp2 -> 0: padded slot contributes 0
            }
        }
        lcf[tid*4 + 0] = make_float4(c[0][0], c[1][0], c[0][1], c[1][1]);
        lcf[tid*4 + 1] = make_float4(c[0][2], c[1][2], c[0][3], c[1][3]);
        lcf[tid*4 + 2] = make_float4(c[0][4], c[1][4], c[0][5], c[1][5]);
        lcf[tid*4 + 3] = make_float4(c[0][6], c[1][6], 0.0f, 0.0f);
    }

    // ---- Per-point setup for 4 points ----
    const int lane = tid & 63;
    const int part = tid >> 6;            // 0..7, wave-uniform
    const int base = blockIdx.x * 256;

    v2f px[4], py[4], qx[4], qy[4], dxv[4], dyv[4], Kv[4];
    #pragma unroll
    for (int t = 0; t < 4; ++t) {
        int i  = base + t * 64 + lane;
        int ii = (i < N) ? i : (N > 0 ? N - 1 : 0);
        float2 o = ((const float2*)origins)[ii];
        float2 d = ((const float2*)directions)[ii];
        px[t] = mk2(o.x, o.x); py[t] = mk2(o.y, o.y);
        qx[t] = px[t] * px[t]; qy[t] = py[t] * py[t];
        dxv[t] = mk2(d.x, d.x); dyv[t] = mk2(d.y, d.y);
        float K = CD * fmaf(d.y, d.y, d.x * d.x);
        Kv[t] = mk2(K, K);
    }

    __syncthreads();

    // ---- Phase 2: sum this wave's pair-chunk for all 4 points ----
    const int chunk = (P + 7) >> 3;
    int pb = part * chunk;
    int pe = pb + chunk; if (pe > P) pe = P;
    pb = __builtin_amdgcn_readfirstlane(pb);
    pe = __builtin_amdgcn_readfirstlane(pe);

    v2f acc[4];
    #pragma unroll
    for (int t = 0; t < 4; ++t) acc[t] = mk2(0.0f, 0.0f);

    #pragma unroll 2
    for (int p = pb; p < pe; ++p) {
        float4 a0 = lcf[4*p + 0];
        float4 a1 = lcf[4*p + 1];
        float4 a2 = lcf[4*p + 2];
        float4 a3 = lcf[4*p + 3];
        v2f w0 = mk2(a0.x, a0.y), w1 = mk2(a0.z, a0.w);
        v2f w2 = mk2(a1.x, a1.y), w3 = mk2(a1.z, a1.w);
        v2f w4 = mk2(a2.x, a2.y), w5 = mk2(a2.z, a2.w);
        v2f w6 = mk2(a3.x, a3.y);

        #pragma unroll
        for (int t = 0; t < 4; ++t) {
            v2f e = w6 + Kv[t];
            e = __builtin_elementwise_fma(w0, qx[t],  e);
            e = __builtin_elementwise_fma(w1, qy[t],  e);
            e = __builtin_elementwise_fma(w2, px[t],  e);
            e = __builtin_elementwise_fma(w3, py[t],  e);
            e = __builtin_elementwise_fma(w4, dxv[t], e);
            e = __builtin_elementwise_fma(w5, dyv[t], e);
            acc[t] += mk2(EXP2F(e.x), EXP2F(e.y));
        }
    }

    #pragma unroll
    for (int t = 0; t < 4; ++t)
        psum[part * 256 + t * 64 + lane] = acc[t].x + acc[t].y;
    __syncthreads();

    // ---- Final reduce: 256 threads, one point each ----
    if (tid < 256) {
        int i = base + tid;
        if (i < N) {
            float t = 0.0f;
            #pragma unroll
            for (int k = 0; k < 8; ++k) t += psum[k * 256 + tid];
            out[i] = fminf(fmaxf(t, 0.0f), 1.0f);
        }
    }
}

extern "C" void kernel_launch(void* const* d_in, const int* in_sizes, int n_in,
                              void* d_out, int out_size, void* d_ws, size_t ws_size,
                              hipStream_t stream) {
    const float* origins    = (const float*)d_in[0];
    const float* directions = (const float*)d_in[1];
    const float* latents    = (const float*)d_in[2];
    float* out = (float*)d_out;

    int N = in_sizes[0] / 2;
    int M = in_sizes[2] / 6;
    if (M > 2 * MAXP) M = 2 * MAXP;   // problem spec: M = 512
    int P = (M + 1) / 2;              // Gaussian pairs (padded)

    int nblocks = (N + 255) / 256;
    decoder_fused<<<nblocks, 512, 0, stream>>>(origins, directions, latents,
                                               out, N, M, P);
}

// Round 7
// 14.119 us; speedup vs baseline: 1.0659x; 1.0659x over previous
//
#include <hip/hip_runtime.h>

#if __has_builtin(__builtin_amdgcn_exp2f)
#define EXP2F(x) __builtin_amdgcn_exp2f(x)
#else
#define EXP2F(x) exp2f(x)
#endif

typedef float v2f __attribute__((ext_vector_type(2)));

constexpr float L2E = 1.4426950408889634f;
constexpr float CD  = -500.0f * L2E;   // -0.5/0.001 * log2(e)
#define MAXP 256                       // max Gaussian pairs (M <= 512)

static __device__ __forceinline__ v2f mk2(float x, float y) {
    v2f r; r.x = x; r.y = y; return r;
}

// Single fused kernel. Block = 1024 threads = 16 waves, covers 128 points
// (2 points per thread). Grid = N/128 = 512 blocks = 2 blocks/CU
// -> 32 waves/CU = MAX occupancy (8 waves/SIMD) for latency hiding.
// Phase 1: threads 0..P-1 expand one Gaussian PAIR each into LDS
//          (pair-transposed coefficients, 4 x float4 per pair).
// Phase 2: wave w sums pair-chunk w (P/16 pairs) for its 2x64 points via
//          broadcast ds_read_b128 (wave-uniform address -> conflict-free).
// exponent(log2) = c0*px^2 + c1*py^2 + c2*px + c3*py + c4*dx + c5*dy + c6 + K
__global__ __launch_bounds__(1024, 2)
void decoder_fused(const float* __restrict__ origins,
                   const float* __restrict__ directions,
                   const float* __restrict__ latents,
                   float* __restrict__ out, int N, int M, int P)
{
    __shared__ float4 lcf[MAXP * 4];
    __shared__ float  psum[16 * 128];   // [wave][pt*64 + lane]

    const int tid = threadIdx.x;

    // ---- Phase 1: expand coefficients into LDS (once per block) ----
    if (tid < P) {
        float c[2][7];
        #pragma unroll
        for (int h = 0; h < 2; ++h) {
            int j = 2 * tid + h;
            if (j < M) {
                const float* L = latents + j * 6;
                float mx = L[0], my = L[1], mdx = L[2], mdy = L[3];
                float A = (-0.5f * L2E) / (fmaxf(L[4], 0.0f) + 0.01f);
                float B = (-0.5f * L2E) / (fmaxf(L[5], 0.0f) + 0.01f);
                c[h][0] = A;
                c[h][1] = B;
                c[h][2] = -2.0f * A * mx;
                c[h][3] = -2.0f * B * my;
                c[h][4] = -2.0f * CD * mdx;
                c[h][5] = -2.0f * CD * mdy;
                c[h][6] = A*mx*mx + B*my*my + CD*(mdx*mdx + mdy*mdy);
            } else {
                c[h][0] = c[h][1] = c[h][2] = c[h][3] = c[h][4] = c[h][5] = 0.0f;
                c[h][6] = -3.0e38f;   // exp2 -> 0: padded slot contributes 0
            }
        }
        lcf[tid*4 + 0] = make_float4(c[0][0], c[1][0], c[0][1], c[1][1]);
        lcf[tid*4 + 1] = make_float4(c[0][2], c[1][2], c[0][3], c[1][3]);
        lcf[tid*4 + 2] = make_float4(c[0][4], c[1][4], c[0][5], c[1][5]);
        lcf[tid*4 + 3] = make_float4(c[0][6], c[1][6], 0.0f, 0.0f);
    }

    // ---- Per-point setup for 2 points ----
    const int lane = tid & 63;
    const int part = tid >> 6;            // 0..15, wave-uniform
    const int base = blockIdx.x * 128;
    const int i0   = base + lane;
    const int i1   = base + 64 + lane;
    const int ii0  = (i0 < N) ? i0 : (N > 0 ? N - 1 : 0);
    const int ii1  = (i1 < N) ? i1 : (N > 0 ? N - 1 : 0);

    const float2 oA = ((const float2*)origins)[ii0];
    const float2 dA = ((const float2*)directions)[ii0];
    const float2 oB = ((const float2*)origins)[ii1];
    const float2 dB = ((const float2*)directions)[ii1];

    const v2f pxA = mk2(oA.x, oA.x), pyA = mk2(oA.y, oA.y);
    const v2f qxA = pxA * pxA,        qyA = pyA * pyA;
    const v2f dxA = mk2(dA.x, dA.x), dyA = mk2(dA.y, dA.y);
    const float KA = CD * fmaf(dA.y, dA.y, dA.x * dA.x);
    const v2f KA2 = mk2(KA, KA);

    const v2f pxB = mk2(oB.x, oB.x), pyB = mk2(oB.y, oB.y);
    const v2f qxB = pxB * pxB,        qyB = pyB * pyB;
    const v2f dxB = mk2(dB.x, dB.x), dyB = mk2(dB.y, dB.y);
    const float KB = CD * fmaf(dB.y, dB.y, dB.x * dB.x);
    const v2f KB2 = mk2(KB, KB);

    __syncthreads();

    // ---- Phase 2: sum this wave's pair-chunk for both points ----
    const int chunk = (P + 15) >> 4;
    int pb = part * chunk;
    int pe = pb + chunk; if (pe > P) pe = P;
    pb = __builtin_amdgcn_readfirstlane(pb);
    pe = __builtin_amdgcn_readfirstlane(pe);

    v2f accA = mk2(0.0f, 0.0f), accB = mk2(0.0f, 0.0f);

    #pragma unroll 2
    for (int p = pb; p < pe; ++p) {
        float4 a0 = lcf[4*p + 0];
        float4 a1 = lcf[4*p + 1];
        float4 a2 = lcf[4*p + 2];
        float4 a3 = lcf[4*p + 3];
        v2f w0 = mk2(a0.x, a0.y), w1 = mk2(a0.z, a0.w);
        v2f w2 = mk2(a1.x, a1.y), w3 = mk2(a1.z, a1.w);
        v2f w4 = mk2(a2.x, a2.y), w5 = mk2(a2.z, a2.w);
        v2f w6 = mk2(a3.x, a3.y);

        v2f eA = w6 + KA2;
        eA = __builtin_elementwise_fma(w0, qxA, eA);
        eA = __builtin_elementwise_fma(w1, qyA, eA);
        eA = __builtin_elementwise_fma(w2, pxA, eA);
        eA = __builtin_elementwise_fma(w3, pyA, eA);
        eA = __builtin_elementwise_fma(w4, dxA, eA);
        eA = __builtin_elementwise_fma(w5, dyA, eA);

        v2f eB = w6 + KB2;
        eB = __builtin_elementwise_fma(w0, qxB, eB);
        eB = __builtin_elementwise_fma(w1, qyB, eB);
        eB = __builtin_elementwise_fma(w2, pxB, eB);
        eB = __builtin_elementwise_fma(w3, pyB, eB);
        eB = __builtin_elementwise_fma(w4, dxB, eB);
        eB = __builtin_elementwise_fma(w5, dyB, eB);

        accA += mk2(EXP2F(eA.x), EXP2F(eA.y));
        accB += mk2(EXP2F(eB.x), EXP2F(eB.y));
    }

    psum[part * 128 + lane]      = accA.x + accA.y;
    psum[part * 128 + 64 + lane] = accB.x + accB.y;
    __syncthreads();

    if (tid < 128) {
        int i = base + tid;
        if (i < N) {
            float t = 0.0f;
            #pragma unroll
            for (int k = 0; k < 16; ++k) t += psum[k * 128 + tid];
            out[i] = fminf(fmaxf(t, 0.0f), 1.0f);
        }
    }
}

extern "C" void kernel_launch(void* const* d_in, const int* in_sizes, int n_in,
                              void* d_out, int out_size, void* d_ws, size_t ws_size,
                              hipStream_t stream) {
    const float* origins    = (const float*)d_in[0];
    const float* directions = (const float*)d_in[1];
    const float* latents    = (const float*)d_in[2];
    float* out = (float*)d_out;

    int N = in_sizes[0] / 2;
    int M = in_sizes[2] / 6;
    if (M > 2 * MAXP) M = 2 * MAXP;   // problem spec: M = 512
    int P = (M + 1) / 2;              // Gaussian pairs (padded)

    int nblocks = (N + 127) / 128;
    decoder_fused<<<nblocks, 1024, 0, stream>>>(origins, directions, latents,
                                                out, N, M, P);
}